// Round 3
// baseline (773.092 us; speedup 1.0000x reference)
//
#include <hip/hip_runtime.h>
#include <hip/hip_bf16.h>
#include <stdint.h>

typedef unsigned short u16;
typedef __bf16 bf16x8 __attribute__((ext_vector_type(8)));
typedef float f32x4 __attribute__((ext_vector_type(4)));
typedef float f32x8 __attribute__((ext_vector_type(8)));

#define BM 128
#define BN 128
#define BK 64

struct SegArgs {
  const float* W[4];
  const float* b[4];
  void* out[4];
  int act[4];      // 0=none 1=sigmoid 2=tanh 3=relu
  int bf16out[4];  // 1 = store bf16 (u16), 0 = store fp32
};

__device__ __forceinline__ float bf2f(u16 u) {
  union { unsigned int i; float f; } v; v.i = ((unsigned int)u) << 16; return v.f;
}
__device__ __forceinline__ u16 f2bf(float f) {
  union { float f; unsigned int i; } v; v.f = f;
  return (u16)((v.i + 0x7fffu + ((v.i >> 16) & 1u)) >> 16);
}
__device__ __forceinline__ uint4 cvt8(f32x8 v) {
  uint4 r;
  r.x = (unsigned)f2bf(v[0]) | ((unsigned)f2bf(v[1]) << 16);
  r.y = (unsigned)f2bf(v[2]) | ((unsigned)f2bf(v[3]) << 16);
  r.z = (unsigned)f2bf(v[4]) | ((unsigned)f2bf(v[5]) << 16);
  r.w = (unsigned)f2bf(v[6]) | ((unsigned)f2bf(v[7]) << 16);
  return r;
}
__device__ __forceinline__ float actf(float x, int act) {
  if (act == 1) return 1.0f / (1.0f + __expf(-x));
  if (act == 2) {
    float xc = fminf(fmaxf(x, -15.0f), 15.0f);
    float e = __expf(2.0f * xc);
    return (e - 1.0f) / (e + 1.0f);
  }
  if (act == 3) return fmaxf(x, 0.0f);
  return x;
}

// C = act( A @ W^T + b ).  A fp32 [M x K], virtually split at KA0 between
// A0/A1 (concat(x,h) unmaterialized).  W fp32 [Nseg x K] row-major,
// seg = blockIdx.y >> tileShift.  Inputs converted fp32->bf16 (RTNE) during
// LDS staging; mfma_f32_16x16x32_bf16; 128x128 tile, BK=64, XOR bank swizzle.
__global__ __launch_bounds__(256, 2) void gemm_bt(
    const float* __restrict__ A0, const float* __restrict__ A1, int KA0, int K,
    SegArgs segs, int tileShift, int ldOut)
{
  __shared__ u16 As[BM * BK];
  __shared__ u16 Bs[BN * BK];

  const int tid  = threadIdx.x;
  const int lane = tid & 63;
  const int wave = tid >> 6;
  const int mBlock = blockIdx.x * BM;
  const int seg   = blockIdx.y >> tileShift;
  const int nTile = blockIdx.y & ((1 << tileShift) - 1);

  const float* Wp = segs.W[seg];
  const int wm = wave & 1, wn = wave >> 1;

  const f32x4 zero = {0.f, 0.f, 0.f, 0.f};
  f32x4 acc[4][4];
#pragma unroll
  for (int i = 0; i < 4; ++i)
#pragma unroll
    for (int j = 0; j < 4; ++j) acc[i][j] = zero;

  for (int kb = 0; kb < K; kb += BK) {
    const float* Aseg; int ka; int ldA;
    if (kb < KA0) { Aseg = A0; ka = kb;       ldA = KA0; }
    else          { Aseg = A1; ka = kb - KA0; ldA = K - KA0; }

    // ---- stage 128x64 A and B tiles (fp32 -> bf16), 4 slots/thread each ----
    f32x8 va[4], vb[4];
#pragma unroll
    for (int it = 0; it < 4; ++it) {
      int s = it * 256 + tid;
      int m = s >> 3;
      int p = s & 7;
      int kc = p ^ (m & 7);
      va[it] = *(const f32x8*)(Aseg + (size_t)(mBlock + m) * (size_t)ldA + (ka + kc * 8));
      vb[it] = *(const f32x8*)(Wp + (size_t)(nTile * BN + m) * (size_t)K + (kb + kc * 8));
    }
#pragma unroll
    for (int it = 0; it < 4; ++it) {
      int s = it * 256 + tid;
      *(uint4*)&As[s * 8] = cvt8(va[it]);
      *(uint4*)&Bs[s * 8] = cvt8(vb[it]);
    }
    __syncthreads();

    // ---- MFMA: A frag [m=lane&15][k=(lane>>4)*8+j], B symmetric ----
#pragma unroll
    for (int ko = 0; ko < 2; ++ko) {
      bf16x8 af[4], bfr[4];
      int kcb = ko * 4 + (lane >> 4);
      int p = kcb ^ (lane & 7);            // (ml&7)==(lane&7): tiles step by 16
#pragma unroll
      for (int t = 0; t < 4; ++t) {
        int ml = wm * 64 + t * 16 + (lane & 15);
        af[t]  = *(const bf16x8*)&As[(ml * 8 + p) * 8];
        int nl = wn * 64 + t * 16 + (lane & 15);
        bfr[t] = *(const bf16x8*)&Bs[(nl * 8 + p) * 8];
      }
#pragma unroll
      for (int tm = 0; tm < 4; ++tm)
#pragma unroll
        for (int tn = 0; tn < 4; ++tn)
          acc[tm][tn] = __builtin_amdgcn_mfma_f32_16x16x32_bf16(af[tm], bfr[tn], acc[tm][tn], 0, 0, 0);
    }
    __syncthreads();
  }

  // epilogue: +bias, activation.  C/D map: col=lane&15, row=(lane>>4)*4+r
  const float* bp = segs.b[seg];
  const int act = segs.act[seg];
  const int isBf = segs.bf16out[seg];
  u16*   opb = (u16*)segs.out[seg];
  float* opf = (float*)segs.out[seg];
  const int q  = lane >> 4;
  const int cl = lane & 15;
#pragma unroll
  for (int tn = 0; tn < 4; ++tn) {
    int col = nTile * BN + wn * 64 + tn * 16 + cl;
    float bv = bp[col];
#pragma unroll
    for (int tm = 0; tm < 4; ++tm) {
      int row = mBlock + wm * 64 + tm * 16 + q * 4;
#pragma unroll
      for (int r = 0; r < 4; ++r) {
        float v = actf(acc[tm][tn][r] + bv, act);
        size_t idx = (size_t)(row + r) * (size_t)ldOut + col;
        if (isBf) opb[idx] = f2bf(v); else opf[idx] = v;
      }
    }
  }
}

// combine activated gates (bf16): c_new = f*c0 + cand*i ; h_new = o*tanh(cand)
// cold/hout/cout fp32.
__global__ void lstm_ew(const u16* __restrict__ gates, const float* __restrict__ cold,
                        float* __restrict__ hout, float* __restrict__ cout, int n)
{
  int i0 = (blockIdx.x * blockDim.x + threadIdx.x) * 8;
  if (i0 >= n) return;
  union U { uint4 v; u16 u[8]; };
  U F, I, C, O;
  F.v = *(const uint4*)(gates + i0);
  I.v = *(const uint4*)(gates + (size_t)n + i0);
  C.v = *(const uint4*)(gates + 2 * (size_t)n + i0);
  O.v = *(const uint4*)(gates + 3 * (size_t)n + i0);
  f32x8 c0v = *(const f32x8*)(cold + i0);
  f32x8 H, CN;
#pragma unroll
  for (int j = 0; j < 8; ++j) {
    float f  = bf2f(F.u[j]);
    float ig = bf2f(I.u[j]);
    float cd = bf2f(C.u[j]);   // already tanh'd, in (-1,1)
    float o  = bf2f(O.u[j]);
    float cn = f * c0v[j] + cd * ig;
    float e  = __expf(2.0f * cd);
    float th = (e - 1.0f) / (e + 1.0f);
    H[j]  = o * th;            // faithful double-tanh
    CN[j] = cn;
  }
  *(f32x8*)(hout + i0) = H;
  *(f32x8*)(cout + i0) = CN;
}

extern "C" void kernel_launch(void* const* d_in, const int* in_sizes, int n_in,
                              void* d_out, int out_size, void* d_ws, size_t ws_size,
                              hipStream_t stream)
{
  const size_t P = 4096ull * 1024ull;  // 4,194,304

  const float* X   = (const float*)d_in[0];
  const float* h1i = (const float*)d_in[1];
  const float* h2i = (const float*)d_in[2];
  const float* c1i = (const float*)d_in[3];
  const float* c2i = (const float*)d_in[4];
  const float* Wf1 = (const float*)d_in[5];  const float* bf1_ = (const float*)d_in[6];
  const float* Wi1 = (const float*)d_in[7];  const float* bi1_ = (const float*)d_in[8];
  const float* Wc1 = (const float*)d_in[9];  const float* bc1_ = (const float*)d_in[10];
  const float* Wo1 = (const float*)d_in[11]; const float* bo1_ = (const float*)d_in[12];
  const float* Wf2 = (const float*)d_in[13]; const float* bf2_ = (const float*)d_in[14];
  const float* Wi2 = (const float*)d_in[15]; const float* bi2_ = (const float*)d_in[16];
  const float* Wc2 = (const float*)d_in[17]; const float* bc2_ = (const float*)d_in[18];
  const float* Wo2 = (const float*)d_in[19]; const float* bo2_ = (const float*)d_in[20];
  const float* W3  = (const float*)d_in[21]; const float* b3_  = (const float*)d_in[22];
  const float* W4  = (const float*)d_in[23]; const float* b4_  = (const float*)d_in[24];

  float* out = (float*)d_out;     // [4096,1024] fp32
  float* h1  = out + P;
  float* h2  = out + 2 * P;
  float* c1  = out + 3 * P;
  float* c2  = out + 4 * P;

  u16*   gates = (u16*)d_ws;                  // 4*P bf16 = 32 MB
  float* out3  = (float*)((char*)d_ws + 4 * P * sizeof(u16));  // 4096*2048 fp32 = 32 MB

  dim3 blk(256, 1, 1);

  // ---- LSTM layer 1: 4 fused gate GEMMs (seg=gate), N=4096, K=2048 ----
  SegArgs s1;
  s1.W[0]=Wf1; s1.W[1]=Wi1; s1.W[2]=Wc1; s1.W[3]=Wo1;
  s1.b[0]=bf1_; s1.b[1]=bi1_; s1.b[2]=bc1_; s1.b[3]=bo1_;
  s1.out[0]=gates; s1.out[1]=gates+P; s1.out[2]=gates+2*P; s1.out[3]=gates+3*P;
  s1.act[0]=1; s1.act[1]=1; s1.act[2]=2; s1.act[3]=1;
  s1.bf16out[0]=s1.bf16out[1]=s1.bf16out[2]=s1.bf16out[3]=1;
  gemm_bt<<<dim3(32,32,1), blk, 0, stream>>>(X, h1i, 1024, 2048, s1, 3, 1024);
  lstm_ew<<<dim3(2048,1,1), blk, 0, stream>>>(gates, c1i, h1, c1, (int)P);

  // ---- LSTM layer 2 (A = [h1 | h2i]) ----
  SegArgs s2 = s1;
  s2.W[0]=Wf2; s2.W[1]=Wi2; s2.W[2]=Wc2; s2.W[3]=Wo2;
  s2.b[0]=bf2_; s2.b[1]=bi2_; s2.b[2]=bc2_; s2.b[3]=bo2_;
  gemm_bt<<<dim3(32,32,1), blk, 0, stream>>>(h1, h2i, 1024, 2048, s2, 3, 1024);
  lstm_ew<<<dim3(2048,1,1), blk, 0, stream>>>(gates, c2i, h2, c2, (int)P);

  // ---- head: out3 = relu(h2 @ W3^T + b3), N=2048, K=1024, fp32 out ----
  SegArgs s3;
  for (int g = 0; g < 4; ++g) { s3.W[g]=W3; s3.b[g]=b3_; s3.out[g]=out3; s3.act[g]=3; s3.bf16out[g]=0; }
  gemm_bt<<<dim3(32,16,1), blk, 0, stream>>>(h2, (const float*)nullptr, 1024, 1024, s3, 4, 2048);

  // ---- head: out = out3 @ W4^T + b4, N=1024, K=2048, fp32 out ----
  SegArgs s4;
  for (int g = 0; g < 4; ++g) { s4.W[g]=W4; s4.b[g]=b4_; s4.out[g]=out; s4.act[g]=0; s4.bf16out[g]=0; }
  gemm_bt<<<dim3(32,8,1), blk, 0, stream>>>(out3, (const float*)nullptr, 2048, 2048, s4, 3, 1024);
}

// Round 4
// 482.346 us; speedup vs baseline: 1.6028x; 1.6028x over previous
//
#include <hip/hip_runtime.h>
#include <hip/hip_bf16.h>
#include <stdint.h>

typedef unsigned short u16;
typedef __bf16 bf16x8 __attribute__((ext_vector_type(8)));
typedef float f32x4 __attribute__((ext_vector_type(4)));
typedef float f32x8 __attribute__((ext_vector_type(8)));

#define BM 128
#define BN 128
#define BK 64

struct SegArgs {
  const u16* W[4];
  const float* b[4];
  void* out[4];
  int act[4];      // 0=none 1=sigmoid 2=tanh 3=relu
  int bf16out[4];  // 1 = store bf16, 0 = store fp32
};

__device__ __forceinline__ float bf2f(u16 u) {
  union { unsigned int i; float f; } v; v.i = ((unsigned int)u) << 16; return v.f;
}
__device__ __forceinline__ u16 f2bf(float f) {
  union { float f; unsigned int i; } v; v.f = f;
  return (u16)((v.i + 0x7fffu + ((v.i >> 16) & 1u)) >> 16);
}
__device__ __forceinline__ uint4 cvt8(f32x8 v) {
  uint4 r;
  r.x = (unsigned)f2bf(v[0]) | ((unsigned)f2bf(v[1]) << 16);
  r.y = (unsigned)f2bf(v[2]) | ((unsigned)f2bf(v[3]) << 16);
  r.z = (unsigned)f2bf(v[4]) | ((unsigned)f2bf(v[5]) << 16);
  r.w = (unsigned)f2bf(v[6]) | ((unsigned)f2bf(v[7]) << 16);
  return r;
}
__device__ __forceinline__ float actf(float x, int act) {
  if (act == 1) return 1.0f / (1.0f + __expf(-x));
  if (act == 2) {
    float xc = fminf(fmaxf(x, -15.0f), 15.0f);
    float e = __expf(2.0f * xc);
    return (e - 1.0f) / (e + 1.0f);
  }
  if (act == 3) return fmaxf(x, 0.0f);
  return x;
}

// ---- bulk fp32 -> bf16 convert; chunk = 2M elements, blockIdx.y = chunk ----
struct CvtArgs { const float* src[10]; u16* dst[10]; };
__global__ void cvt_f2b(CvtArgs a) {
  const float* s = a.src[blockIdx.y];
  u16* d = a.dst[blockIdx.y];
  int i0 = (blockIdx.x * 256 + threadIdx.x) * 8;
  f32x8 v = *(const f32x8*)(s + i0);
  *(uint4*)(d + i0) = cvt8(v);
}

// C = act( A @ W^T + b ).  A bf16 [M x K], virtually split at KA0 between
// A0/A1 (concat(x,h) unmaterialized).  W bf16 [Nseg x K] row-major,
// seg = blockIdx.y >> tileShift.  m97 structure: 128x128 tile, BK=64,
// global_load_lds width=16 staging, XOR bank swizzle, mfma_f32_16x16x32_bf16.
__global__ __launch_bounds__(256, 2) void gemm_bt(
    const u16* __restrict__ A0, const u16* __restrict__ A1, int KA0, int K,
    SegArgs segs, int tileShift, int ldOut)
{
  __shared__ u16 As[BM * BK];
  __shared__ u16 Bs[BN * BK];

  const int tid  = threadIdx.x;
  const int lane = tid & 63;
  const int wave = tid >> 6;
  const int mBlock = blockIdx.x * BM;
  const int seg   = blockIdx.y >> tileShift;
  const int nTile = blockIdx.y & ((1 << tileShift) - 1);

  const u16* Wp = segs.W[seg];
  const int wm = wave & 1, wn = wave >> 1;

  const f32x4 zero = {0.f, 0.f, 0.f, 0.f};
  f32x4 acc[4][4];
#pragma unroll
  for (int i = 0; i < 4; ++i)
#pragma unroll
    for (int j = 0; j < 4; ++j) acc[i][j] = zero;

  for (int kb = 0; kb < K; kb += BK) {
    const u16* Aseg; int ka; int ldA;
    if (kb < KA0) { Aseg = A0; ka = kb;       ldA = KA0; }
    else          { Aseg = A1; ka = kb - KA0; ldA = K - KA0; }

    // stage 128x64 tiles: slot s=it*256+tid holds row m=s>>3,
    // chunk kc=(s&7)^(m&7) (XOR bank swizzle).  global_load_lds places
    // lane's 16B at wave-uniform base + lane*16 -> slot s exactly.
#pragma unroll
    for (int it = 0; it < 4; ++it) {
      int s = it * 256 + tid;
      int m = s >> 3;
      int p = s & 7;
      int kc = p ^ (m & 7);
      const u16* srcA = Aseg + (size_t)(mBlock + m) * (size_t)ldA + (ka + kc * 8);
      const u16* srcB = Wp + (size_t)(nTile * BN + m) * (size_t)K + (kb + kc * 8);
      u16* dA = &As[(it * 256 + wave * 64) * 8];
      u16* dB = &Bs[(it * 256 + wave * 64) * 8];
      __builtin_amdgcn_global_load_lds((void*)srcA, (void*)dA, 16, 0, 0);
      __builtin_amdgcn_global_load_lds((void*)srcB, (void*)dB, 16, 0, 0);
    }
    __syncthreads();

    // MFMA: A frag [m=lane&15][k=(lane>>4)*8+j], B symmetric
#pragma unroll
    for (int ko = 0; ko < 2; ++ko) {
      bf16x8 af[4], bfr[4];
      int kcb = ko * 4 + (lane >> 4);
      int p = kcb ^ (lane & 7);            // (ml&7)==(lane&7): tiles step by 16
#pragma unroll
      for (int t = 0; t < 4; ++t) {
        int ml = wm * 64 + t * 16 + (lane & 15);
        af[t]  = *(const bf16x8*)&As[(ml * 8 + p) * 8];
        int nl = wn * 64 + t * 16 + (lane & 15);
        bfr[t] = *(const bf16x8*)&Bs[(nl * 8 + p) * 8];
      }
#pragma unroll
      for (int tm = 0; tm < 4; ++tm)
#pragma unroll
        for (int tn = 0; tn < 4; ++tn)
          acc[tm][tn] = __builtin_amdgcn_mfma_f32_16x16x32_bf16(af[tm], bfr[tn], acc[tm][tn], 0, 0, 0);
    }
    __syncthreads();
  }

  // epilogue: +bias, activation.  C/D map: col=lane&15, row=(lane>>4)*4+r
  const float* bp = segs.b[seg];
  const int act = segs.act[seg];
  const int isBf = segs.bf16out[seg];
  u16*   opb = (u16*)segs.out[seg];
  float* opf = (float*)segs.out[seg];
  const int q  = lane >> 4;
  const int cl = lane & 15;
#pragma unroll
  for (int tn = 0; tn < 4; ++tn) {
    int col = nTile * BN + wn * 64 + tn * 16 + cl;
    float bv = bp[col];
#pragma unroll
    for (int tm = 0; tm < 4; ++tm) {
      int row = mBlock + wm * 64 + tm * 16 + q * 4;
#pragma unroll
      for (int r = 0; r < 4; ++r) {
        float v = actf(acc[tm][tn][r] + bv, act);
        size_t idx = (size_t)(row + r) * (size_t)ldOut + col;
        if (isBf) opb[idx] = f2bf(v); else opf[idx] = v;
      }
    }
  }
}

// combine gates (bf16): c_new = f*c0 + cand*i ; h_new = o*tanh(cand).
// writes h/c fp32 (outputs) + h bf16 (next GEMM's A-side).
__global__ void lstm_ew(const u16* __restrict__ gates, const float* __restrict__ cold,
                        float* __restrict__ hout, float* __restrict__ cout,
                        u16* __restrict__ hb, int n)
{
  int i0 = (blockIdx.x * blockDim.x + threadIdx.x) * 8;
  if (i0 >= n) return;
  union U { uint4 v; u16 u[8]; };
  U F, I, C, O;
  F.v = *(const uint4*)(gates + i0);
  I.v = *(const uint4*)(gates + (size_t)n + i0);
  C.v = *(const uint4*)(gates + 2 * (size_t)n + i0);
  O.v = *(const uint4*)(gates + 3 * (size_t)n + i0);
  f32x8 c0v = *(const f32x8*)(cold + i0);
  f32x8 H, CN;
#pragma unroll
  for (int j = 0; j < 8; ++j) {
    float f  = bf2f(F.u[j]);
    float ig = bf2f(I.u[j]);
    float cd = bf2f(C.u[j]);   // already tanh'd, in (-1,1)
    float o  = bf2f(O.u[j]);
    float cn = f * c0v[j] + cd * ig;
    float e  = __expf(2.0f * cd);
    float th = (e - 1.0f) / (e + 1.0f);
    H[j]  = o * th;            // faithful double-tanh
    CN[j] = cn;
  }
  *(f32x8*)(hout + i0) = H;
  *(f32x8*)(cout + i0) = CN;
  *(uint4*)(hb + i0) = cvt8(H);
}

extern "C" void kernel_launch(void* const* d_in, const int* in_sizes, int n_in,
                              void* d_out, int out_size, void* d_ws, size_t ws_size,
                              hipStream_t stream)
{
  const size_t P   = 4096ull * 1024ull;  // 4,194,304 elements
  const size_t C2M = 2097152ull;         // cvt chunk = 2M elements

  const float* X   = (const float*)d_in[0];
  const float* h1i = (const float*)d_in[1];
  const float* h2i = (const float*)d_in[2];
  const float* c1i = (const float*)d_in[3];
  const float* c2i = (const float*)d_in[4];
  const float* Wf1 = (const float*)d_in[5];  const float* bf1_ = (const float*)d_in[6];
  const float* Wi1 = (const float*)d_in[7];  const float* bi1_ = (const float*)d_in[8];
  const float* Wc1 = (const float*)d_in[9];  const float* bc1_ = (const float*)d_in[10];
  const float* Wo1 = (const float*)d_in[11]; const float* bo1_ = (const float*)d_in[12];
  const float* Wf2 = (const float*)d_in[13]; const float* bf2_ = (const float*)d_in[14];
  const float* Wi2 = (const float*)d_in[15]; const float* bi2_ = (const float*)d_in[16];
  const float* Wc2 = (const float*)d_in[17]; const float* bc2_ = (const float*)d_in[18];
  const float* Wo2 = (const float*)d_in[19]; const float* bo2_ = (const float*)d_in[20];
  const float* W3  = (const float*)d_in[21]; const float* b3_  = (const float*)d_in[22];
  const float* W4  = (const float*)d_in[23]; const float* b4_  = (const float*)d_in[24];

  float* out = (float*)d_out;     // fp32 outputs (reference dtype)
  float* h1  = out + P;
  float* h2  = out + 2 * P;
  float* c1  = out + 3 * P;
  float* c2  = out + 4 * P;

  // ws layout (80 MB), phase-aliased:
  //  D @  0MB (32): gates bf16          (GEMM1->ew1, GEMM2->ew2)
  //  A @ 32MB (16): W1b -> W2b -> out3b
  //  B @ 48MB ( 8): Xb  -> h2ib
  //  Cg@ 56MB ( 8): h1ib -> h2b
  //  E @ 64MB ( 8): h1b
  //  F @ 72MB ( 8): W3b (4) + W4b (4)
  char* ws = (char*)d_ws;
  u16* gates = (u16*)ws;
  u16* Areg  = (u16*)(ws + (32ull << 20));
  u16* Breg  = (u16*)(ws + (48ull << 20));
  u16* Creg  = (u16*)(ws + (56ull << 20));
  u16* Ereg  = (u16*)(ws + (64ull << 20));
  u16* Freg  = (u16*)(ws + (72ull << 20));

  dim3 blk(256, 1, 1);

  // ---- cvtA: W1 gates, X, h1i, W3, W4 -> bf16 ----
  CvtArgs ca;
  ca.src[0]=Wf1;        ca.dst[0]=Areg;
  ca.src[1]=Wi1;        ca.dst[1]=Areg + C2M;
  ca.src[2]=Wc1;        ca.dst[2]=Areg + 2*C2M;
  ca.src[3]=Wo1;        ca.dst[3]=Areg + 3*C2M;
  ca.src[4]=X;          ca.dst[4]=Breg;
  ca.src[5]=X + C2M;    ca.dst[5]=Breg + C2M;
  ca.src[6]=h1i;        ca.dst[6]=Creg;
  ca.src[7]=h1i + C2M;  ca.dst[7]=Creg + C2M;
  ca.src[8]=W3;         ca.dst[8]=Freg;
  ca.src[9]=W4;         ca.dst[9]=Freg + C2M;
  cvt_f2b<<<dim3(1024, 10, 1), blk, 0, stream>>>(ca);

  // ---- LSTM layer 1: fused 4-gate GEMM (N=4096, K=2048) ----
  SegArgs s1;
  s1.W[0]=Areg; s1.W[1]=Areg+C2M; s1.W[2]=Areg+2*C2M; s1.W[3]=Areg+3*C2M;
  s1.b[0]=bf1_; s1.b[1]=bi1_; s1.b[2]=bc1_; s1.b[3]=bo1_;
  s1.out[0]=gates; s1.out[1]=gates+P; s1.out[2]=gates+2*P; s1.out[3]=gates+3*P;
  s1.act[0]=1; s1.act[1]=1; s1.act[2]=2; s1.act[3]=1;
  s1.bf16out[0]=s1.bf16out[1]=s1.bf16out[2]=s1.bf16out[3]=1;
  gemm_bt<<<dim3(32,32,1), blk, 0, stream>>>(Breg, Creg, 1024, 2048, s1, 3, 1024);
  lstm_ew<<<dim3(2048,1,1), blk, 0, stream>>>(gates, c1i, h1, c1, Ereg, (int)P);

  // ---- cvtB: W2 gates, h2i -> bf16 (overwrite A/B regions) ----
  CvtArgs cb;
  cb.src[0]=Wf2;        cb.dst[0]=Areg;
  cb.src[1]=Wi2;        cb.dst[1]=Areg + C2M;
  cb.src[2]=Wc2;        cb.dst[2]=Areg + 2*C2M;
  cb.src[3]=Wo2;        cb.dst[3]=Areg + 3*C2M;
  cb.src[4]=h2i;        cb.dst[4]=Breg;
  cb.src[5]=h2i + C2M;  cb.dst[5]=Breg + C2M;
  cvt_f2b<<<dim3(1024, 6, 1), blk, 0, stream>>>(cb);

  // ---- LSTM layer 2: A = [h1b | h2ib] ----
  SegArgs s2 = s1;
  s2.b[0]=bf2_; s2.b[1]=bi2_; s2.b[2]=bc2_; s2.b[3]=bo2_;
  gemm_bt<<<dim3(32,32,1), blk, 0, stream>>>(Ereg, Breg, 1024, 2048, s2, 3, 1024);
  lstm_ew<<<dim3(2048,1,1), blk, 0, stream>>>(gates, c2i, h2, c2, Creg, (int)P);

  // ---- head: out3b = relu(h2b @ W3^T + b3), N=2048, K=1024, bf16 out -> A ----
  SegArgs s3;
  for (int g = 0; g < 4; ++g) { s3.W[g]=Freg; s3.b[g]=b3_; s3.out[g]=Areg; s3.act[g]=3; s3.bf16out[g]=1; }
  gemm_bt<<<dim3(32,16,1), blk, 0, stream>>>(Creg, (const u16*)nullptr, 1024, 1024, s3, 4, 2048);

  // ---- head: out = out3b @ W4^T + b4, N=1024, K=2048, fp32 out ----
  SegArgs s4;
  for (int g = 0; g < 4; ++g) { s4.W[g]=Freg+C2M; s4.b[g]=b4_; s4.out[g]=out; s4.act[g]=0; s4.bf16out[g]=0; }
  gemm_bt<<<dim3(32,8,1), blk, 0, stream>>>(Areg, (const u16*)nullptr, 2048, 2048, s4, 3, 1024);
}